// Round 3
// baseline (356.872 us; speedup 1.0000x reference)
//
#include <hip/hip_runtime.h>
#include <hip/hip_bf16.h>
#include <math.h>

#define H_DIM 288
#define NHEADS 18
#define HEAD_D 16
#define SEQ 2048
#define BATCH 2
#define M_TOT (BATCH*SEQ)   // 4096

typedef __hip_bfloat16 bf16;

__device__ __forceinline__ float b2f(bf16 x) { return __bfloat162float(x); }

// Dtype-adaptive input load: flag==1 -> buffer holds bf16, else fp32.
__device__ __forceinline__ float ldin(const void* p, size_t i, int isbf) {
    return isbf ? b2f(((const bf16*)p)[i]) : ((const float*)p)[i];
}

// ---------------------------------------------------------------------------
// Input-dtype detector: read first 256 u16 of hidden_states as bf16.
// True bf16 N(0,1) data -> ~256 "plausible"; fp32 read as bf16 -> ~143.
// R2 result proved fp32 (flag=0 path taken), detector kept for safety.
// ---------------------------------------------------------------------------
__global__ void detect_dtype(const unsigned short* __restrict__ x, int* __restrict__ flag)
{
    int lane = threadIdx.x;   // 64 threads
    int cnt = 0;
    for (int i = 0; i < 4; i++) {
        unsigned short u = x[lane + 64*i];
        unsigned int bits = ((unsigned int)u) << 16;
        float v = __uint_as_float(bits);
        float a = fabsf(v);
        bool good = (v == 0.0f) || (a > 1e-6f && a < 1000.0f);
        cnt += __popcll(__ballot(good));
    }
    if (lane == 0) *flag = (cnt >= 200) ? 1 : 0;
}

// ---------------------------------------------------------------------------
// QKV projection: C[m][n] = sum_h X[m][h] * W[n][h]  (y = x @ W^T)
// ---------------------------------------------------------------------------
__global__ __launch_bounds__(256) void qkv_gemm(
    const void* __restrict__ X,
    const void* __restrict__ Wq, const void* __restrict__ Wk, const void* __restrict__ Wv,
    float* __restrict__ Qo, float* __restrict__ Ko, float* __restrict__ Vo,
    const int* __restrict__ flagp)
{
    const int isbf = *flagp;
    const int z = blockIdx.z;
    const void* W = (z == 0) ? Wq : (z == 1) ? Wk : Wv;
    float* O = (z == 0) ? Qo : (z == 1) ? Ko : Vo;

    __shared__ float Xs[64][33];
    __shared__ float Ws[32][33];

    const int n0 = blockIdx.x * 32;
    const int m0 = blockIdx.y * 64;
    const int t  = threadIdx.x;
    const int lr = t >> 5, lc = t & 31;
    const int tn = t & 15, tm = t >> 4;

    float acc[4][2] = {};

    for (int k0 = 0; k0 < H_DIM; k0 += 32) {
        #pragma unroll
        for (int i = 0; i < 8; i++)
            Xs[lr + 8*i][lc] = ldin(X, (size_t)(m0 + lr + 8*i)*H_DIM + k0 + lc, isbf);
        #pragma unroll
        for (int i = 0; i < 4; i++)
            Ws[lr + 8*i][lc] = ldin(W, (size_t)(n0 + lr + 8*i)*H_DIM + k0 + lc, isbf);
        __syncthreads();
        #pragma unroll
        for (int kk = 0; kk < 32; kk++) {
            float b0 = Ws[tn][kk], b1 = Ws[tn + 16][kk];
            #pragma unroll
            for (int i = 0; i < 4; i++) {
                float a = Xs[tm + 16*i][kk];
                acc[i][0] = fmaf(a, b0, acc[i][0]);
                acc[i][1] = fmaf(a, b1, acc[i][1]);
            }
        }
        __syncthreads();
    }
    #pragma unroll
    for (int i = 0; i < 4; i++) {
        int m = m0 + tm + 16*i;
        int bb = m >> 11, s = m & (SEQ - 1);
        #pragma unroll
        for (int j = 0; j < 2; j++) {
            int n = n0 + tn + 16*j;
            int head = n >> 4, d = n & 15;
            O[((size_t)(bb*NHEADS + head)*SEQ + s)*HEAD_D + d] = acc[i][j];
        }
    }
}

// ---------------------------------------------------------------------------
// Output projection: out[m][n] = sum_h O[m][h] * Wo[n][h], fp32 store
// ---------------------------------------------------------------------------
__global__ __launch_bounds__(256) void out_gemm(
    const float* __restrict__ X, const void* __restrict__ W, float* __restrict__ C,
    const int* __restrict__ flagp)
{
    const int isbf = *flagp;
    __shared__ float Xs[64][33];
    __shared__ float Ws[32][33];

    const int n0 = blockIdx.x * 32;
    const int m0 = blockIdx.y * 64;
    const int t  = threadIdx.x;
    const int lr = t >> 5, lc = t & 31;
    const int tn = t & 15, tm = t >> 4;

    float acc[4][2] = {};

    for (int k0 = 0; k0 < H_DIM; k0 += 32) {
        #pragma unroll
        for (int i = 0; i < 8; i++)
            Xs[lr + 8*i][lc] = X[(size_t)(m0 + lr + 8*i)*H_DIM + k0 + lc];
        #pragma unroll
        for (int i = 0; i < 4; i++)
            Ws[lr + 8*i][lc] = ldin(W, (size_t)(n0 + lr + 8*i)*H_DIM + k0 + lc, isbf);
        __syncthreads();
        #pragma unroll
        for (int kk = 0; kk < 32; kk++) {
            float b0 = Ws[tn][kk], b1 = Ws[tn + 16][kk];
            #pragma unroll
            for (int i = 0; i < 4; i++) {
                float a = Xs[tm + 16*i][kk];
                acc[i][0] = fmaf(a, b0, acc[i][0]);
                acc[i][1] = fmaf(a, b1, acc[i][1]);
            }
        }
        __syncthreads();
    }
    #pragma unroll
    for (int i = 0; i < 4; i++) {
        int m = m0 + tm + 16*i;
        #pragma unroll
        for (int j = 0; j < 2; j++) {
            int n = n0 + tn + 16*j;
            C[(size_t)m*H_DIM + n] = acc[i][j];
        }
    }
}

// ---------------------------------------------------------------------------
// RoPE in-place on Q and K (fp32 workspace).
// ---------------------------------------------------------------------------
__global__ __launch_bounds__(256) void rope_kernel(float* __restrict__ Q, float* __restrict__ K)
{
    const int PAIRS = BATCH*NHEADS*SEQ*8;
    int idx = blockIdx.x * 256 + threadIdx.x;
    float* Mt = (idx >= PAIRS) ? K : Q;
    int p = (idx >= PAIRS) ? idx - PAIRS : idx;
    int i = p & 7;
    int s = (p >> 3) & (SEQ - 1);
    int base = (p >> 3) * HEAD_D;
    float inv_freq = exp2f(-1.6609640474436813f * (float)i);  // log2(10000)/8
    float ang = (float)s * inv_freq;
    float c, sn;
    sincosf(ang, &sn, &c);
    float x0 = Mt[base + i], x1 = Mt[base + i + 8];
    Mt[base + i]     = x0*c - x1*sn;
    Mt[base + i + 8] = x1*c + x0*sn;
}

// ---------------------------------------------------------------------------
// Flash-style causal attention, fp32.
// ---------------------------------------------------------------------------
__global__ __launch_bounds__(256) void attn_kernel(
    const float* __restrict__ Q, const float* __restrict__ K, const float* __restrict__ V,
    float* __restrict__ O)
{
    const int bh   = blockIdx.y;
    const int q0   = blockIdx.x * 16;
    const int wave = threadIdx.x >> 6;
    const int lane = threadIdx.x & 63;
    const int b = bh / NHEADS, h = bh % NHEADS;

    const float* Kb = K + (size_t)bh * SEQ * HEAD_D;
    const float* Vb = V + (size_t)bh * SEQ * HEAD_D;
    const float* Qb = Q + (size_t)bh * SEQ * HEAD_D;

    __shared__ float KsT[HEAD_D * 64];
    __shared__ float VsT[HEAD_D * 64];
    __shared__ float red[4][16][17];

    const int r0 = q0 + wave * 4;
    float q[4][HEAD_D];
    #pragma unroll
    for (int r = 0; r < 4; r++)
        #pragma unroll
        for (int d = 0; d < HEAD_D; d++)
            q[r][d] = Qb[(size_t)(r0 + r)*HEAD_D + d] * 0.25f;  // fold 1/sqrt(16)

    float acc[4][HEAD_D] = {};
    float l[4] = {0.f, 0.f, 0.f, 0.f};

    const int jmax = q0 + 16;
    for (int j0 = 0; j0 < jmax; j0 += 64) {
        __syncthreads();
        {
            const int tt = threadIdx.x;
            float4 kx = ((const float4*)(Kb + (size_t)j0*HEAD_D))[tt];
            float4 vx = ((const float4*)(Vb + (size_t)j0*HEAD_D))[tt];
            int j = tt >> 2, d0 = (tt & 3) * 4;
            KsT[(d0+0)*64 + j] = kx.x; KsT[(d0+1)*64 + j] = kx.y;
            KsT[(d0+2)*64 + j] = kx.z; KsT[(d0+3)*64 + j] = kx.w;
            VsT[(d0+0)*64 + j] = vx.x; VsT[(d0+1)*64 + j] = vx.y;
            VsT[(d0+2)*64 + j] = vx.z; VsT[(d0+3)*64 + j] = vx.w;
        }
        __syncthreads();

        float sc[4] = {0.f, 0.f, 0.f, 0.f};
        #pragma unroll
        for (int d = 0; d < HEAD_D; d++) {
            float kd = KsT[d*64 + lane];
            #pragma unroll
            for (int r = 0; r < 4; r++) sc[r] = fmaf(q[r][d], kd, sc[r]);
        }
        float vv[HEAD_D];
        #pragma unroll
        for (int d = 0; d < HEAD_D; d++) vv[d] = VsT[d*64 + lane];

        const int j = j0 + lane;
        #pragma unroll
        for (int r = 0; r < 4; r++) {
            float p = (j <= r0 + r) ? __expf(sc[r]) : 0.0f;
            l[r] += p;
            #pragma unroll
            for (int d = 0; d < HEAD_D; d++) acc[r][d] = fmaf(p, vv[d], acc[r][d]);
        }
    }

    #pragma unroll
    for (int r = 0; r < 4; r++) {
        #pragma unroll
        for (int d = 0; d < HEAD_D; d++) {
            acc[r][d] += __shfl_xor(acc[r][d], 16, 64);
            acc[r][d] += __shfl_xor(acc[r][d], 32, 64);
        }
        float lr_ = l[r];
        #pragma unroll
        for (int off = 1; off <= 32; off <<= 1)
            lr_ += __shfl_xor(lr_, off, 64);
        if (lane < 16) {
            #pragma unroll
            for (int d = 0; d < HEAD_D; d++) red[wave][lane][d] = acc[r][d];
            float tot = 0.f;
            #pragma unroll
            for (int jj = 0; jj < 16; jj++) tot += red[wave][jj][lane];
            O[((size_t)(b*SEQ + r0 + r))*H_DIM + h*HEAD_D + lane] = tot / lr_;
        }
    }
}

// ---------------------------------------------------------------------------
extern "C" void kernel_launch(void* const* d_in, const int* in_sizes, int n_in,
                              void* d_out, int out_size, void* d_ws, size_t ws_size,
                              hipStream_t stream)
{
    const void* Xh = d_in[0];
    const void* Wq = d_in[1];
    const void* Wk = d_in[2];
    const void* Wv = d_in[3];
    const void* Wo = d_in[4];
    float* out = (float*)d_out;   // reference output dtype is float32

    const size_t MAT = (size_t)M_TOT * H_DIM;   // 1179648 floats
    int*   flag = (int*)d_ws;                   // first 256 B reserved
    float* Q = (float*)d_ws + 64;
    float* K = Q + MAT;
    float* V = K + MAT;
    float* O = V + MAT;

    detect_dtype<<<1, 64, 0, stream>>>((const unsigned short*)Xh, flag);
    qkv_gemm<<<dim3(9, 64, 3), 256, 0, stream>>>(Xh, Wq, Wk, Wv, Q, K, V, flag);
    rope_kernel<<<dim3((2*BATCH*NHEADS*SEQ*8)/256), 256, 0, stream>>>(Q, K);
    attn_kernel<<<dim3(SEQ/16, BATCH*NHEADS), 256, 0, stream>>>(Q, K, V, O);
    out_gemm<<<dim3(9, 64), 256, 0, stream>>>(O, Wo, out, flag);
}